// Round 7
// baseline (234.020 us; speedup 1.0000x reference)
//
#include <hip/hip_runtime.h>

// CenterLoss: out = mean_i sqrt( sum_d (x[i,d] - weight[targets[i],d])^2 + EPS )
// x: [N=65536, D=512] f32, weight: [C=1000, D=512] f32, targets: [N] i32.
//
// R7: bucket-by-class. The R3/R5 null (dur 199.9 vs 200.1) showed the kernel
// is not latency-bound; theory is the per-row weight gather doubles TA-port
// traffic (128 MB x + 128 MB w through the CU memory port ~= 42+ us at
// 10 B/cyc/CU). Bucketing rows by class lets each block register-cache its
// class center once: w traffic 128 MB -> ~8 MB, port traffic halves.
// Pipeline: memset(counts) -> histogram -> scan -> scatter -> main.

typedef float f32x4 __attribute__((ext_vector_type(4)));

constexpr int D = 512;
constexpr float EPS = 1e-6f;

// ---- ws layout (ints): [0,1024)=counts [1024,2048)=offsets
//                        [2048,3072)=cursors [3072, 3072+N)=bucket rowids
__global__ void k_count(const int* __restrict__ targets, int n,
                        int* __restrict__ counts) {
    int i = blockIdx.x * blockDim.x + threadIdx.x;
    if (i < n) atomicAdd(&counts[targets[i]], 1);
}

__global__ __launch_bounds__(1024) void k_scan(const int* __restrict__ counts,
                                               int* __restrict__ offsets,
                                               int* __restrict__ cursors, int C) {
    __shared__ int s[1024];
    const int tid = threadIdx.x;
    const int cnt = (tid < C) ? counts[tid] : 0;
    s[tid] = cnt;
    __syncthreads();
    // Hillis-Steele inclusive scan over 1024 entries
    for (int off = 1; off < 1024; off <<= 1) {
        int v = (tid >= off) ? s[tid - off] : 0;
        __syncthreads();
        s[tid] += v;
        __syncthreads();
    }
    if (tid < C) {
        const int excl = s[tid] - cnt;
        offsets[tid] = excl;
        cursors[tid] = excl;
    }
}

__global__ void k_scatter(const int* __restrict__ targets, int n,
                          int* __restrict__ cursors, int* __restrict__ bucket) {
    int i = blockIdx.x * blockDim.x + threadIdx.x;
    if (i < n) {
        int pos = atomicAdd(&cursors[targets[i]], 1);
        bucket[pos] = i;
    }
}

// One block per class; 4 waves split the class's rows; center in registers.
__global__ __launch_bounds__(256) void k_main(
    const float* __restrict__ x, const float* __restrict__ w,
    const int* __restrict__ offsets, const int* __restrict__ counts,
    const int* __restrict__ bucket, float* __restrict__ out, float inv_n)
{
    const int lane = threadIdx.x & 63;
    const int wave = threadIdx.x >> 6;
    const int c = blockIdx.x;
    const int start = offsets[c];
    const int cnt   = counts[c];

    // Class center: 512 floats = 64 lanes x 2 float4, loaded ONCE.
    const f32x4* __restrict__ wr = reinterpret_cast<const f32x4*>(w + (size_t)c * D);
    const f32x4 wa = wr[lane];
    const f32x4 wb = wr[lane + 64];

    float wsum = 0.0f;

    // Prefetch the rowid one iteration ahead (wave-uniform scalar load).
    int row = (wave < cnt) ? bucket[start + wave] : 0;
    for (int j = wave; j < cnt; j += 4) {
        const int nrow = (j + 4 < cnt) ? bucket[start + j + 4] : 0;

        const f32x4* __restrict__ xr =
            reinterpret_cast<const f32x4*>(x + (size_t)row * D);
        const f32x4 xa = __builtin_nontemporal_load(&xr[lane]);
        const f32x4 xb = __builtin_nontemporal_load(&xr[lane + 64]);

        float a = 0.0f, d;
        d = xa.x - wa.x; a = fmaf(d, d, a);
        d = xa.y - wa.y; a = fmaf(d, d, a);
        d = xa.z - wa.z; a = fmaf(d, d, a);
        d = xa.w - wa.w; a = fmaf(d, d, a);
        d = xb.x - wb.x; a = fmaf(d, d, a);
        d = xb.y - wb.y; a = fmaf(d, d, a);
        d = xb.z - wb.z; a = fmaf(d, d, a);
        d = xb.w - wb.w; a = fmaf(d, d, a);

        #pragma unroll
        for (int off = 1; off < 64; off <<= 1)
            a += __shfl_xor(a, off, 64);

        wsum += sqrtf(a + EPS);
        row = nrow;
    }

    __shared__ float smem[4];
    if (lane == 0) smem[wave] = wsum;
    __syncthreads();
    if (threadIdx.x == 0) {
        atomicAdd(out, (smem[0] + smem[1] + smem[2] + smem[3]) * inv_n);
    }
}

extern "C" void kernel_launch(void* const* d_in, const int* in_sizes, int n_in,
                              void* d_out, int out_size, void* d_ws, size_t ws_size,
                              hipStream_t stream) {
    const float* x       = (const float*)d_in[0];
    const float* weight  = (const float*)d_in[1];
    const int*   targets = (const int*)d_in[2];
    float* out = (float*)d_out;

    const int n_rows = in_sizes[2];           // 65536
    const int C      = in_sizes[1] / D;       // 1000

    int* ws_i    = (int*)d_ws;
    int* counts  = ws_i;
    int* offsets = ws_i + 1024;
    int* cursors = ws_i + 2048;
    int* bucket  = ws_i + 3072;

    // d_out / d_ws are poisoned 0xAA before every call.
    (void)hipMemsetAsync(d_out, 0, sizeof(float), stream);
    (void)hipMemsetAsync(counts, 0, 1024 * sizeof(int), stream);

    const int tblk = 256;
    const int tgrid = (n_rows + tblk - 1) / tblk;          // 256
    k_count  <<<tgrid, tblk, 0, stream>>>(targets, n_rows, counts);
    k_scan   <<<1, 1024, 0, stream>>>(counts, offsets, cursors, C);
    k_scatter<<<tgrid, tblk, 0, stream>>>(targets, n_rows, cursors, bucket);
    k_main   <<<C, 256, 0, stream>>>(x, weight, offsets, counts, bucket,
                                     out, 1.0f / (float)n_rows);
}